// Round 1
// 414.798 us; speedup vs baseline: 1.0828x; 1.0828x over previous
//
#include <hip/hip_runtime.h>
#include <cstdint>
#include <cstddef>

typedef int i32x4 __attribute__((ext_vector_type(4)));

#define BM 256
#define BN 256
#define BK 64   // bytes of K per tile; one mfma_i32_16x16x64_i8 covers the whole tile-K

__device__ __forceinline__ void load16_to_lds(const void* g, void* l) {
  __builtin_amdgcn_global_load_lds(
      (const __attribute__((address_space(1))) void*)g,
      (__attribute__((address_space(3))) void*)l,
      16, 0, 0);
}

// Fused input quantization.
// Blocks [0, M): per-row absmax + int8 quantize of x (row held in regs).
// Blocks [M, M + N*K/4096): pack int32 weights (values in [-127,127]) to int8.
__global__ __launch_bounds__(256) void quant_xw(const float* __restrict__ x,
                                                char* __restrict__ xq,
                                                float* __restrict__ sx,
                                                const int* __restrict__ w,
                                                char* __restrict__ wq,
                                                int M, int K) {
  const int t = threadIdx.x;
  __shared__ float red[4];
  if ((int)blockIdx.x < M) {
    const int row = blockIdx.x;
    const float* xr = x + (size_t)row * K;
    float4 v[4];
    float amax = 0.f;
#pragma unroll
    for (int j = 0; j < 4; ++j) {
      v[j] = ((const float4*)xr)[t + j * 256];
      amax = fmaxf(amax, fmaxf(fmaxf(fabsf(v[j].x), fabsf(v[j].y)),
                               fmaxf(fabsf(v[j].z), fabsf(v[j].w))));
    }
#pragma unroll
    for (int off = 32; off; off >>= 1)
      amax = fmaxf(amax, __shfl_xor(amax, off));
    if ((t & 63) == 0) red[t >> 6] = amax;
    __syncthreads();
    amax = fmaxf(fmaxf(red[0], red[1]), fmaxf(red[2], red[3]));
    amax = fmaxf(amax, 1e-20f);

    const float s = 127.0f / amax;
    int* outw = (int*)(xq + (size_t)row * K);
#pragma unroll
    for (int j = 0; j < 4; ++j) {
      int q0 = __float2int_rn(v[j].x * s);
      int q1 = __float2int_rn(v[j].y * s);
      int q2 = __float2int_rn(v[j].z * s);
      int q3 = __float2int_rn(v[j].w * s);
      int pk = (q0 & 0xff) | ((q1 & 0xff) << 8) | ((q2 & 0xff) << 16) | ((q3 & 0xff) << 24);
      outw[t + j * 256] = pk;
    }
    if (t == 0) sx[row] = amax * (1.0f / 127.0f);
  } else {
    const size_t base = (size_t)(blockIdx.x - M) * 4096;
    int* outw = (int*)(wq + base);
#pragma unroll
    for (int j = 0; j < 4; ++j) {
      const int c = t + j * 256;
      int4 a = ((const int4*)(w + base))[c];
      outw[c] = (a.x & 0xff) | ((a.y & 0xff) << 8) | ((a.z & 0xff) << 16) | ((a.w & 0xff) << 24);
    }
  }
}

// C[m][n] = sum_k A[m][k]*Bw[n][k] (int8 -> int32); out = C*sx[m]*sw[n] + bias[n].
// 256x256 tile, 512 thr (8 waves: 2M x 4N), BK=64B, phase-split schedule:
//   3-buffer LDS rotation; tile t+2 staged during tile t's compute into the buffer
//   tile t-1 finished reading (WAR-safe via the tile-boundary barrier).
//   Counted vmcnt(4) at tile boundary (never 0 in steady state) keeps t+2's loads
//   in flight across barriers. 2 phases x 16 MFMA per tile, setprio(1) around MFMA.
// LDS swizzle (carried from verified kernel): 16B chunk (row r, k-chunk j) stored at
//   byte r*64 + ((j ^ ((r>>1)&3))*16); staged via pre-swizzled global source so the
//   global_load_lds destination stays linear (lane*16).
__global__ __launch_bounds__(512) void gemm_i8_bt(const char* __restrict__ A,
                                                  const char* __restrict__ Bw,
                                                  const float* __restrict__ sx,
                                                  const float* __restrict__ sw,
                                                  const float* __restrict__ bias,
                                                  float* __restrict__ out,
                                                  int M, int N, int K) {
  __shared__ __align__(16) char As[3][BM * BK];   // 3 x 16 KiB
  __shared__ __align__(16) char Bs[3][BN * BK];   // 3 x 16 KiB  (96 KiB total)

  const int tid  = threadIdx.x;
  const int wave = tid >> 6;
  const int lane = tid & 63;
  const int wm   = wave >> 2;      // 0..1 -> 128-row half
  const int wn   = wave & 3;       // 0..3 -> 64-col quarter

  // XCD-aware bijective block swizzle (nwg = 512, 512 % 8 == 0 so simple form is bijective)
  const int gx   = N / BN;                              // 16
  const int nwg  = gx * (M / BM);                       // 512
  const int orig = blockIdx.y * gx + blockIdx.x;
  const int wg   = (orig & 7) * (nwg >> 3) + (orig >> 3);
  const int bn   = wg % gx;
  const int bm   = wg / gx;

  i32x4 acc[8][4] = {};

  // Staging: thread stages 16B chunks q=tid and q=tid+512 of each tile.
  // Chunk q -> LDS byte q*16, global (row q>>2, k-chunk (q&3)^((q>>3)&3)).
  const int rowT = tid >> 2;
  const int jg   = ((tid & 3) ^ ((tid >> 3) & 3)) << 4;
  const char* Ag1 = A  + (size_t)(bm * BM + rowT) * K + jg;
  const char* Ag2 = Ag1 + (size_t)128 * K;
  const char* Bg1 = Bw + (size_t)(bn * BN + rowT) * K + jg;
  const char* Bg2 = Bg1 + (size_t)128 * K;

  const int ldsO1 = wave << 10;             // chunk q=tid      -> byte tid*16
  const int ldsO2 = 8192 + (wave << 10);    // chunk q=tid+512

  // Fragment read offsets: row R, k-chunk j=lane>>4 at byte R*64 + (j^((R>>1)&3))*16.
  // ((R>>1)&3) == ((fr>>1)&3) since wm*128 and m*16 contribute 0 mod the relevant bits.
  const int fr  = lane & 15;
  const int swz = (((lane >> 4) ^ ((fr >> 1) & 3)) << 4);
  int offA[8], offB[4];
#pragma unroll
  for (int m = 0; m < 8; ++m) offA[m] = (wm * 128 + m * 16 + fr) * 64 + swz;
#pragma unroll
  for (int n = 0; n < 4; ++n) offB[n] = (wn * 64 + n * 16 + fr) * 64 + swz;

  const int NT = K / BK;    // 64

  // Prologue: stage tiles 0,1 into buffers 0,1; wait tile 0 (keep tile 1 in flight).
  load16_to_lds(Ag1,      &As[0][ldsO1]);
  load16_to_lds(Ag2,      &As[0][ldsO2]);
  load16_to_lds(Bg1,      &Bs[0][ldsO1]);
  load16_to_lds(Bg2,      &Bs[0][ldsO2]);
  load16_to_lds(Ag1 + BK, &As[1][ldsO1]);
  load16_to_lds(Ag2 + BK, &As[1][ldsO2]);
  load16_to_lds(Bg1 + BK, &Bs[1][ldsO1]);
  load16_to_lds(Bg2 + BK, &Bs[1][ldsO2]);
  asm volatile("s_waitcnt vmcnt(4)" ::: "memory");
  __builtin_amdgcn_s_barrier();

  int buf = 0;                              // tile t lives in buffer t % 3
  for (int t = 0; t < NT; ++t) {
    const int  nb = (buf >= 1) ? buf - 1 : 2;      // (t+2) % 3
    const size_t ko = (size_t)(t + 2) * BK;
    const bool pf = (t + 2) < NT;

    // ---------- phase A: A-frags m0-3 + all B-frags; stage next A half-pair ----------
    i32x4 af0 = *(const i32x4*)&As[buf][offA[0]];
    i32x4 af1 = *(const i32x4*)&As[buf][offA[1]];
    i32x4 af2 = *(const i32x4*)&As[buf][offA[2]];
    i32x4 af3 = *(const i32x4*)&As[buf][offA[3]];
    i32x4 bf0 = *(const i32x4*)&Bs[buf][offB[0]];
    i32x4 bf1 = *(const i32x4*)&Bs[buf][offB[1]];
    i32x4 bf2 = *(const i32x4*)&Bs[buf][offB[2]];
    i32x4 bf3 = *(const i32x4*)&Bs[buf][offB[3]];
    if (pf) {
      load16_to_lds(Ag1 + ko, &As[nb][ldsO1]);
      load16_to_lds(Ag2 + ko, &As[nb][ldsO2]);
    }
    __builtin_amdgcn_s_barrier();
    asm volatile("s_waitcnt lgkmcnt(0)" ::: "memory");
    __builtin_amdgcn_sched_barrier(0);
    __builtin_amdgcn_s_setprio(1);
    acc[0][0] = __builtin_amdgcn_mfma_i32_16x16x64_i8(af0, bf0, acc[0][0], 0, 0, 0);
    acc[0][1] = __builtin_amdgcn_mfma_i32_16x16x64_i8(af0, bf1, acc[0][1], 0, 0, 0);
    acc[0][2] = __builtin_amdgcn_mfma_i32_16x16x64_i8(af0, bf2, acc[0][2], 0, 0, 0);
    acc[0][3] = __builtin_amdgcn_mfma_i32_16x16x64_i8(af0, bf3, acc[0][3], 0, 0, 0);
    acc[1][0] = __builtin_amdgcn_mfma_i32_16x16x64_i8(af1, bf0, acc[1][0], 0, 0, 0);
    acc[1][1] = __builtin_amdgcn_mfma_i32_16x16x64_i8(af1, bf1, acc[1][1], 0, 0, 0);
    acc[1][2] = __builtin_amdgcn_mfma_i32_16x16x64_i8(af1, bf2, acc[1][2], 0, 0, 0);
    acc[1][3] = __builtin_amdgcn_mfma_i32_16x16x64_i8(af1, bf3, acc[1][3], 0, 0, 0);
    acc[2][0] = __builtin_amdgcn_mfma_i32_16x16x64_i8(af2, bf0, acc[2][0], 0, 0, 0);
    acc[2][1] = __builtin_amdgcn_mfma_i32_16x16x64_i8(af2, bf1, acc[2][1], 0, 0, 0);
    acc[2][2] = __builtin_amdgcn_mfma_i32_16x16x64_i8(af2, bf2, acc[2][2], 0, 0, 0);
    acc[2][3] = __builtin_amdgcn_mfma_i32_16x16x64_i8(af2, bf3, acc[2][3], 0, 0, 0);
    acc[3][0] = __builtin_amdgcn_mfma_i32_16x16x64_i8(af3, bf0, acc[3][0], 0, 0, 0);
    acc[3][1] = __builtin_amdgcn_mfma_i32_16x16x64_i8(af3, bf1, acc[3][1], 0, 0, 0);
    acc[3][2] = __builtin_amdgcn_mfma_i32_16x16x64_i8(af3, bf2, acc[3][2], 0, 0, 0);
    acc[3][3] = __builtin_amdgcn_mfma_i32_16x16x64_i8(af3, bf3, acc[3][3], 0, 0, 0);
    __builtin_amdgcn_s_setprio(0);
    __builtin_amdgcn_s_barrier();

    // ---------- phase B: A-frags m4-7; stage next B half-pair ----------
    i32x4 af4 = *(const i32x4*)&As[buf][offA[4]];
    i32x4 af5 = *(const i32x4*)&As[buf][offA[5]];
    i32x4 af6 = *(const i32x4*)&As[buf][offA[6]];
    i32x4 af7 = *(const i32x4*)&As[buf][offA[7]];
    if (pf) {
      load16_to_lds(Bg1 + ko, &Bs[nb][ldsO1]);
      load16_to_lds(Bg2 + ko, &Bs[nb][ldsO2]);
    }
    __builtin_amdgcn_s_barrier();
    asm volatile("s_waitcnt lgkmcnt(0)" ::: "memory");
    __builtin_amdgcn_sched_barrier(0);
    __builtin_amdgcn_s_setprio(1);
    acc[4][0] = __builtin_amdgcn_mfma_i32_16x16x64_i8(af4, bf0, acc[4][0], 0, 0, 0);
    acc[4][1] = __builtin_amdgcn_mfma_i32_16x16x64_i8(af4, bf1, acc[4][1], 0, 0, 0);
    acc[4][2] = __builtin_amdgcn_mfma_i32_16x16x64_i8(af4, bf2, acc[4][2], 0, 0, 0);
    acc[4][3] = __builtin_amdgcn_mfma_i32_16x16x64_i8(af4, bf3, acc[4][3], 0, 0, 0);
    acc[5][0] = __builtin_amdgcn_mfma_i32_16x16x64_i8(af5, bf0, acc[5][0], 0, 0, 0);
    acc[5][1] = __builtin_amdgcn_mfma_i32_16x16x64_i8(af5, bf1, acc[5][1], 0, 0, 0);
    acc[5][2] = __builtin_amdgcn_mfma_i32_16x16x64_i8(af5, bf2, acc[5][2], 0, 0, 0);
    acc[5][3] = __builtin_amdgcn_mfma_i32_16x16x64_i8(af5, bf3, acc[5][3], 0, 0, 0);
    acc[6][0] = __builtin_amdgcn_mfma_i32_16x16x64_i8(af6, bf0, acc[6][0], 0, 0, 0);
    acc[6][1] = __builtin_amdgcn_mfma_i32_16x16x64_i8(af6, bf1, acc[6][1], 0, 0, 0);
    acc[6][2] = __builtin_amdgcn_mfma_i32_16x16x64_i8(af6, bf2, acc[6][2], 0, 0, 0);
    acc[6][3] = __builtin_amdgcn_mfma_i32_16x16x64_i8(af6, bf3, acc[6][3], 0, 0, 0);
    acc[7][0] = __builtin_amdgcn_mfma_i32_16x16x64_i8(af7, bf0, acc[7][0], 0, 0, 0);
    acc[7][1] = __builtin_amdgcn_mfma_i32_16x16x64_i8(af7, bf1, acc[7][1], 0, 0, 0);
    acc[7][2] = __builtin_amdgcn_mfma_i32_16x16x64_i8(af7, bf2, acc[7][2], 0, 0, 0);
    acc[7][3] = __builtin_amdgcn_mfma_i32_16x16x64_i8(af7, bf3, acc[7][3], 0, 0, 0);
    __builtin_amdgcn_s_setprio(0);

    // Tile boundary: retire tile t+1's 4 loads, keep tile t+2's 4 in flight.
    if (pf)                 { asm volatile("s_waitcnt vmcnt(4)" ::: "memory"); }
    else if (t + 1 < NT)    { asm volatile("s_waitcnt vmcnt(0)" ::: "memory"); }
    __builtin_amdgcn_s_barrier();

    buf = (buf < 2) ? buf + 1 : 0;
  }

  // Epilogue. C/D layout (dtype-independent): col = lane&15, row = (lane>>4)*4 + reg.
  const int colc = lane & 15;
  const int rq   = (lane >> 4) << 2;
  float sxv[8][4];
#pragma unroll
  for (int m = 0; m < 8; ++m) {
    const int row0 = bm * BM + wm * 128 + m * 16 + rq;
#pragma unroll
    for (int r = 0; r < 4; ++r) sxv[m][r] = sx[row0 + r];
  }
#pragma unroll
  for (int n = 0; n < 4; ++n) {
    const int col = bn * BN + wn * 64 + n * 16 + colc;
    const float sc = sw[col];
    const float bi = bias[col];
#pragma unroll
    for (int m = 0; m < 8; ++m) {
      const int row0 = bm * BM + wm * 128 + m * 16 + rq;
#pragma unroll
      for (int r = 0; r < 4; ++r)
        out[(size_t)(row0 + r) * N + col] = (float)acc[m][n][r] * (sxv[m][r] * sc) + bi;
    }
  }
}

extern "C" void kernel_launch(void* const* d_in, const int* in_sizes, int n_in,
                              void* d_out, int out_size, void* d_ws, size_t ws_size,
                              hipStream_t stream) {
  const float* x     = (const float*)d_in[0];
  const int*   w     = (const int*)d_in[1];
  const float* scale = (const float*)d_in[2];
  const float* bias  = (const float*)d_in[3];
  float*       out   = (float*)d_out;

  const int N = in_sizes[3];          // D_OUT = 4096
  const int K = in_sizes[1] / N;      // D_IN  = 4096
  const int M = in_sizes[0] / K;      // B*S   = 8192

  char*  xq = (char*)d_ws;                       // M*K i8  = 32 MiB
  char*  wq = xq + (size_t)M * K;                // N*K i8  = 16 MiB
  float* sx = (float*)(wq + (size_t)N * K);      // M floats

  const unsigned wblocks = (unsigned)(((size_t)N * K) / 4096);
  quant_xw<<<dim3((unsigned)M + wblocks), dim3(256), 0, stream>>>(x, xq, sx, w, wq, M, K);

  gemm_i8_bt<<<dim3(N / BN, M / BM), dim3(512), 0, stream>>>(xq, wq, sx, scale, bias, out, M, N, K);
}